// Round 12
// baseline (213.545 us; speedup 1.0000x reference)
//
#include <hip/hip_runtime.h>
#include <cstdint>
#include <cstddef>

typedef __bf16 bf16;
typedef __bf16 bf16x8 __attribute__((ext_vector_type(8)));
typedef float floatx4 __attribute__((ext_vector_type(4)));
typedef int intx8 __attribute__((ext_vector_type(8)));

#define NB 4096   // batch
#define ND 2048   // feature dim
#define NCLS 64   // classes
#define TSTRIDE 144  // sim epilogue LDS row stride (bytes), 16B-aligned
#define OS 136       // recon epilogue LDS row stride (bf16 elems, 272 B)

// ---------------------------------------------------------------- staging ---
__device__ __forceinline__ void stage16(const void* g, void* l) {
  // async global -> LDS, 16B per lane, LDS dest = wave-uniform base + lane*16
  __builtin_amdgcn_global_load_lds(
      (__attribute__((address_space(1))) unsigned int*)g,
      (__attribute__((address_space(3))) unsigned int*)l, 16, 0, 0);
}

// fp8 e4m3 (OCP) converts, RNE via V_CVT_PK_FP8_F32
__device__ __forceinline__ unsigned char fp8x1(float f) {
  return (unsigned char)(__builtin_amdgcn_cvt_pk_fp8_f32(f, f, 0, false) & 0xFF);
}
__device__ __forceinline__ int fp8x4(float f0, float f1, float f2, float f3) {
  int d = __builtin_amdgcn_cvt_pk_fp8_f32(f0, f1, 0, false);
  return __builtin_amdgcn_cvt_pk_fp8_f32(f2, f3, d, true);
}

// ------------------------------------------------------------- GEMM core ----
// C[128][128] = A[128][K] * B[128][K]^T, fp8, fp32 accum, mfma_scale
// 16x16x128 (scales=1.0 -> 127).
// Post-R11 design: GEMMs are throughput-bound on the staging/fragment path
// (pipelining was null), so maximize FLOP per staged/LDS byte:
//  - 128x128 tile (131 FLOP/staged-byte vs 87 for 128x64).
//  - A operand read DIRECTLY from global per lane (contiguous 32B/frag, no
//    XOR swizzle needed, no A-LDS at all): A panels are XCD-L2-resident by
//    the grid grouping, so these are L2 hits; identical L2 traffic to the
//    old gload_lds staging but deletes A's LDS write+read roundtrip.
//  - LDS = B double-buffer only (2x16KB): proven R2 row-major 128B rows,
//    chunk XOR swizzle, gload_lds staging, ONE __syncthreads per K-step.
//  -> 32KB LDS, single-round grids, 3-4 blocks/CU at (256,3).
// Wave grid 2x2 (wm,wn), per-wave 64x64 output: acc[4][4].
__device__ __forceinline__ void gemm_core128(
    const unsigned char* __restrict__ Abase, int astride, int arow0,
    const unsigned char* __restrict__ Bbase, const int boff[4], int nk,
    unsigned char* __restrict__ Bs0, unsigned char* __restrict__ Bs1,
    floatx4 acc[4][4], int w, int lane) {
  const int wm = w >> 1, wn = w & 1;
  const int lm = lane & 15, quad = lane >> 4;

  int aoffs[4];
#pragma unroll
  for (int i = 0; i < 4; ++i)
    aoffs[i] = (arow0 + wm * 64 + i * 16 + lm) * astride + quad * 32;

  auto STAGEB = [&](int k0, unsigned char* Bs) {
#pragma unroll
    for (int q = 0; q < 4; ++q)
      stage16(Bbase + (size_t)(boff[q] + k0), Bs + w * 4096 + q * 1024);
  };

  STAGEB(0, Bs0);
  for (int k = 0; k < nk; ++k) {
    __syncthreads();  // drains vmcnt(0): B buf[k&1] staged; prior reads done
    if (k + 1 < nk) STAGEB((k + 1) << 7, (k & 1) ? Bs0 : Bs1);
    const unsigned char* Bc = (k & 1) ? Bs1 : Bs0;

    intx8 af[4], bf[4];
#pragma unroll
    for (int i = 0; i < 4; ++i) {  // A: direct global, contiguous 32B
      const int4 lo = *(const int4*)(Abase + (size_t)(aoffs[i] + (k << 7)));
      const int4 hi =
          *(const int4*)(Abase + (size_t)(aoffs[i] + (k << 7) + 16));
      af[i][0] = lo.x; af[i][1] = lo.y; af[i][2] = lo.z; af[i][3] = lo.w;
      af[i][4] = hi.x; af[i][5] = hi.y; af[i][6] = hi.z; af[i][7] = hi.w;
    }
#pragma unroll
    for (int i = 0; i < 4; ++i) {  // B: LDS, proven swizzled layout
      const int row = wn * 64 + i * 16 + lm;
      const int c0 = (quad * 2) ^ (row & 7);
      const int4 lo = *(const int4*)(Bc + row * 128 + c0 * 16);
      const int4 hi = *(const int4*)(Bc + row * 128 + (c0 ^ 1) * 16);
      bf[i][0] = lo.x; bf[i][1] = lo.y; bf[i][2] = lo.z; bf[i][3] = lo.w;
      bf[i][4] = hi.x; bf[i][5] = hi.y; bf[i][6] = hi.z; bf[i][7] = hi.w;
    }
#pragma unroll
    for (int mi = 0; mi < 4; ++mi)
#pragma unroll
      for (int ni = 0; ni < 4; ++ni)
        acc[mi][ni] = __builtin_amdgcn_mfma_scale_f32_16x16x128_f8f6f4(
            af[mi], bf[ni], acc[mi][ni], 0, 0, 0, 127, 0, 127);
  }
}

// ---------------------------------------------------------------- kernels ---

// Compaction: perm = sorted indices i with fs[y[i]]==0 (the only columns that
// survive the softmax mask). minfo = {M, Mp(=ceil128), Mp/128}. Pad perm with
// 0 (valid row) so padded staging never fabricates fp8 NaNs. Also init lrow,
// contrib here (single tiny block, runs before everything else).
__global__ __launch_bounds__(1024) void perm_kernel(
    const int* __restrict__ y, const int* __restrict__ fs,
    const float* __restrict__ c, int* __restrict__ perm,
    int* __restrict__ minfo, float* __restrict__ lrow,
    float* __restrict__ contrib) {
  const int t = threadIdx.x;
  const int base = t * 4;
  int fl[4];
  int cnt = 0;
#pragma unroll
  for (int j = 0; j < 4; ++j) {
    const int yi = y[base + j];
    fl[j] = (fs[yi] == 0) ? 1 : 0;
    cnt += fl[j];
    contrib[base + j] = c[yi];
    lrow[base + j] = 0.0f;
  }
  // inclusive scan of cnt across the block (wave scan + inter-wave sum)
  const int lane = t & 63, w = t >> 6;
  int inc = cnt;
#pragma unroll
  for (int o = 1; o < 64; o <<= 1) {
    int v = __shfl_up(inc, o);
    if (lane >= o) inc += v;
  }
  __shared__ int wsum[16];
  __shared__ int Msh;
  if (lane == 63) wsum[w] = inc;
  __syncthreads();
  int wbase = 0;
  for (int i = 0; i < w; ++i) wbase += wsum[i];
  int pos = wbase + inc - cnt;  // exclusive prefix
#pragma unroll
  for (int j = 0; j < 4; ++j)
    if (fl[j]) perm[pos++] = base + j;
  if (t == 1023) Msh = wbase + inc;
  __syncthreads();
  const int M = Msh;
  const int Mp = (M + 127) & ~127;
  if (t < Mp - M) perm[M + t] = 0;
  if (t == 0) {
    minfo[0] = M;
    minfo[1] = Mp;
    minfo[2] = Mp >> 7;
  }
}

// Fused prep: blocks 0..NB-1 do LayerNorm (x -> XN8 = fp8(x_norm*32));
// blocks NB.. transpose GATHERED rows x[perm[..]] -> XBT8c (fp8, columns
// already compacted; row stride stays NB).
__global__ __launch_bounds__(256) void prep_kernel(
    const float* __restrict__ x, unsigned char* __restrict__ XN8,
    unsigned char* __restrict__ XBT8, const int* __restrict__ perm,
    const int* __restrict__ minfo) {
  __shared__ float tile[64][65];
  const int t = threadIdx.x;

  if (blockIdx.x < NB) {
    // ---------------- LayerNorm branch
    const int row = blockIdx.x;
    const float4* xr = (const float4*)(x + (size_t)row * ND);
    float4 v0 = xr[t], v1 = xr[t + 256];
    float s = v0.x + v0.y + v0.z + v0.w + v1.x + v1.y + v1.z + v1.w;
    float q = v0.x * v0.x + v0.y * v0.y + v0.z * v0.z + v0.w * v0.w +
              v1.x * v1.x + v1.y * v1.y + v1.z * v1.z + v1.w * v1.w;
#pragma unroll
    for (int o = 32; o > 0; o >>= 1) {
      s += __shfl_down(s, o);
      q += __shfl_down(q, o);
    }
    const int w = t >> 6;
    if ((t & 63) == 0) { tile[0][w] = s; tile[1][w] = q; }
    __syncthreads();
    s = tile[0][0] + tile[0][1] + tile[0][2] + tile[0][3];
    q = tile[1][0] + tile[1][1] + tile[1][2] + tile[1][3];
    const float mu = s * (1.0f / ND);
    const float var = q * (1.0f / ND) - mu * mu;
    const float sc =
        rsqrtf(var + 1e-5f) * 0.02209708691207961f * 32.0f;  // /sqrt(2048)*32

    int* orow = (int*)(XN8 + (size_t)row * ND);
    orow[t] = fp8x4((v0.x - mu) * sc, (v0.y - mu) * sc, (v0.z - mu) * sc,
                    (v0.w - mu) * sc);
    orow[256 + t] = fp8x4((v1.x - mu) * sc, (v1.y - mu) * sc, (v1.z - mu) * sc,
                          (v1.w - mu) * sc);
  } else {
    // ---------------- transpose branch: gathered x rows -> XBT8c (ND x NB)
    const int b2 = blockIdx.x - NB;
    const int rb = b2 & 63;  // compacted batch tile (0..63)
    const int cb = b2 >> 6;  // feature tile (0..31)
    if (rb * 64 >= minfo[1]) return;  // beyond Mp: nothing to build
    const int tx = t & 63, ty = t >> 6;
#pragma unroll
    for (int rr = ty; rr < 64; rr += 4)
      tile[rr][tx] = x[(size_t)perm[rb * 64 + rr] * ND + cb * 64 + tx];
    __syncthreads();
    const int ro = t >> 2;  // out row within feature tile
    const int co = t & 3;   // 16-byte chunk within batch tile
    int4 v;
    {
      const int j = co * 16;
      v.x = fp8x4(tile[j + 0][ro], tile[j + 1][ro], tile[j + 2][ro], tile[j + 3][ro]);
      v.y = fp8x4(tile[j + 4][ro], tile[j + 5][ro], tile[j + 6][ro], tile[j + 7][ro]);
      v.z = fp8x4(tile[j + 8][ro], tile[j + 9][ro], tile[j + 10][ro], tile[j + 11][ro]);
      v.w = fp8x4(tile[j + 12][ro], tile[j + 13][ro], tile[j + 14][ro], tile[j + 15][ro]);
    }
    *(int4*)(XBT8 + (size_t)(cb * 64 + ro) * NB + rb * 64 + co * 16) = v;
  }
}

// GEMM1 (rectangular, column-compacted, 128x128 tiles): tile (bi, bjc)
// computes sim[m0..][perm[n0..n0+128]]; B rows gathered through perm at
// stage time; A read direct-from-global (XCD-L2-resident panels).
// e = exp(acc/1024), diag + pad -> 0; write P8 tile fp8; accumulate row
// sums. XCD-grouped: XCD x owns bi {4x..4x+3}, bi fastest -> B tile reused
// x4 from L2. 32 KB LDS -> single round (608 active <= 768+ slots).
__global__ __launch_bounds__(256, 3) void gemm_sim_kernel(
    const unsigned char* __restrict__ XN8, unsigned char* __restrict__ P8,
    float* __restrict__ lrow, const int* __restrict__ perm,
    const int* __restrict__ minfo) {
  __shared__ unsigned char smem[32768];
  unsigned char* Bs0 = smem;
  unsigned char* Bs1 = smem + 16384;

  const int Mp = minfo[1];
  const int id = blockIdx.x;
  const int xcd = id & 7;       // round-robin dispatch -> XCD
  const int s = id >> 3;        // 0..79 within XCD
  const int bi = xcd * 4 + (s & 3);
  const int bjc = s >> 2;       // 0..19 (128-col tiles); inactive exit
  const int n0 = bjc * 128;
  if (n0 >= Mp) return;
  const int M = minfo[0];
  const int m0 = bi * 128;

  const int t = threadIdx.x, w = t >> 6, lane = t & 63;
  const int wm = w >> 1, wn = w & 1, lm = lane & 15, quad = lane >> 4;

  int boff[4];
#pragma unroll
  for (int q = 0; q < 4; ++q) {
    const int slot = w * 256 + q * 64 + lane;
    const int row = slot >> 3;
    const int cc = (slot & 7) ^ (row & 7);
    boff[q] = perm[n0 + row] * ND + cc * 16;  // gathered B rows
  }

  floatx4 acc[4][4];
#pragma unroll
  for (int i = 0; i < 4; ++i)
#pragma unroll
    for (int j = 0; j < 4; ++j) acc[i][j] = 0.0f;

  gemm_core128(XN8, ND, m0, XN8, boff, ND >> 7, Bs0, Bs1, acc, w, lane);

  int pcol[4], valid[4];
#pragma unroll
  for (int ni = 0; ni < 4; ++ni) {
    const int gc = n0 + wn * 64 + ni * 16 + lm;
    valid[ni] = (gc < M) ? 1 : 0;
    pcol[ni] = perm[gc];  // original batch index of this compacted column
  }

  float rs[4][4];
#pragma unroll
  for (int mi = 0; mi < 4; ++mi)
#pragma unroll
    for (int r = 0; r < 4; ++r) rs[mi][r] = 0.0f;

#pragma unroll
  for (int ni = 0; ni < 4; ++ni) {
#pragma unroll
    for (int mi = 0; mi < 4; ++mi) {
#pragma unroll
      for (int r = 0; r < 4; ++r) {
        const int grow = m0 + wm * 64 + mi * 16 + quad * 4 + r;
        const float e = (valid[ni] && grow != pcol[ni])
                            ? __expf(acc[mi][ni][r] * 0.0009765625f)
                            : 0.0f;  // diag / pad column -> exact 0
        acc[mi][ni][r] = e;
        rs[mi][r] += e;
      }
    }
  }
#pragma unroll
  for (int mi = 0; mi < 4; ++mi)
#pragma unroll
    for (int r = 0; r < 4; ++r) {
      float vsum = rs[mi][r];
      vsum += __shfl_xor(vsum, 1);
      vsum += __shfl_xor(vsum, 2);
      vsum += __shfl_xor(vsum, 4);
      vsum += __shfl_xor(vsum, 8);
      if (lm == 0)
        atomicAdd(&lrow[m0 + wm * 64 + mi * 16 + quad * 4 + r], vsum);
    }

  // ---- P tile -> LDS (byte scatter) -> coalesced b128 store at (bi, bjc)
  __syncthreads();  // K-loop's last reads done in all waves; LDS reusable
#pragma unroll
  for (int ni = 0; ni < 4; ++ni) {
    const int col = wn * 64 + ni * 16 + lm;
#pragma unroll
    for (int mi = 0; mi < 4; ++mi)
#pragma unroll
      for (int r = 0; r < 4; ++r) {
        const int row = wm * 64 + mi * 16 + quad * 4 + r;
        smem[row * TSTRIDE + col] = fp8x1(acc[mi][ni][r]);
      }
  }
  __syncthreads();
#pragma unroll
  for (int it = 0; it < 4; ++it) {
    const int row = it * 32 + (t >> 3), ch = t & 7;
    int4 v = *(const int4*)(smem + row * TSTRIDE + ch * 16);
    *(int4*)(P8 + (size_t)(m0 + row) * NB + n0 + ch * 16) = v;
  }
}

// GEMM2 (128x128 tiles): R(bf16) = (P8[:,:Mp] @ XBT8c[:,:Mp]^T)/l * contrib
// + x*(1-contrib). K compacted to Mp. A (P8) direct-from-global, XCD-grouped
// by P8 ROW panels (by): XCD x owns by {4x..4x+3} -> 2 MiB L2-resident;
// by fastest so the 4 by-tiles share each XBT B-tile from L2.
// Grid 512 <= capacity: single round.
__global__ __launch_bounds__(256, 3) void gemm_recon_kernel(
    const unsigned char* __restrict__ P8, const unsigned char* __restrict__ XBT8,
    const float* __restrict__ x, const float* __restrict__ lrow,
    const float* __restrict__ contrib, const int* __restrict__ minfo,
    bf16* __restrict__ R) {
  __shared__ unsigned char smem[36864];  // 32KB B-dbuf; 34.8KB epilogue reuse
  unsigned char* Bs0 = smem;
  unsigned char* Bs1 = smem + 16384;

  const int id = blockIdx.x;
  const int xcd = id & 7;
  const int s = id >> 3;          // 0..63
  const int by = xcd * 4 + (s & 3);
  const int bx = s >> 2;          // 0..15
  const int m0 = by * 128, n0 = bx * 128;

  const int t = threadIdx.x, w = t >> 6, lane = t & 63;
  const int wm = w >> 1, wn = w & 1, lm = lane & 15, quad = lane >> 4;

  int boff[4];
#pragma unroll
  for (int q = 0; q < 4; ++q) {
    const int slot = w * 256 + q * 64 + lane;
    const int row = slot >> 3;
    const int cc = (slot & 7) ^ (row & 7);
    boff[q] = (n0 + row) * NB + cc * 16;
  }

  floatx4 acc[4][4];
#pragma unroll
  for (int i = 0; i < 4; ++i)
#pragma unroll
    for (int j = 0; j < 4; ++j) acc[i][j] = 0.0f;

  gemm_core128(P8, NB, m0, XBT8, boff, minfo[2], Bs0, Bs1, acc, w, lane);

  __syncthreads();  // waves done with K-loop buffers; reuse smem
  bf16* osm = (bf16*)smem;
#pragma unroll
  for (int mi = 0; mi < 4; ++mi) {
#pragma unroll
    for (int r = 0; r < 4; ++r) {
      const int lrow_i = wm * 64 + mi * 16 + quad * 4 + r;
      const int grow = m0 + lrow_i;
      const float inv = 1.0f / lrow[grow];
      const float ci = contrib[grow];
#pragma unroll
      for (int ni = 0; ni < 4; ++ni) {
        const int lcol = wn * 64 + ni * 16 + lm;
        const float rec = acc[mi][ni][r] * inv;
        const float xv = x[(size_t)grow * ND + n0 + lcol];
        osm[lrow_i * OS + lcol] = (bf16)(rec * ci + xv * (1.0f - ci));
      }
    }
  }
  __syncthreads();
#pragma unroll
  for (int it = 0; it < 8; ++it) {
    const int row = it * 16 + (t >> 4), ch = t & 15;
    int4 v = *(const int4*)(osm + row * OS + ch * 8);
    *(int4*)(R + (size_t)(m0 + row) * ND + n0 + ch * 8) = v;
  }
}

// Mix: x_mix = a*R[i] + (1-a)*R[beta[i]] (R in bf16); y_mix from one-hots.
// 2 rows per block (grid NB/2) to cut launch/scheduling overhead.
__global__ __launch_bounds__(256) void mix_kernel(
    const bf16* __restrict__ R, const float* __restrict__ alpha,
    const int* __restrict__ beta_idx, const int* __restrict__ y,
    float* __restrict__ out) {
  const int t = threadIdx.x;
#pragma unroll
  for (int rr = 0; rr < 2; ++rr) {
    const int i = blockIdx.x * 2 + rr;
    const float a = alpha[i];
    const int bi = beta_idx[i];
    const bf16x8* Ri = (const bf16x8*)(R + (size_t)i * ND);
    const bf16x8* Rb = (const bf16x8*)(R + (size_t)bi * ND);
    const float b = 1.0f - a;
    bf16x8 r = Ri[t], g = Rb[t];
    float4 o0, o1;
    o0.x = a * (float)r[0] + b * (float)g[0];
    o0.y = a * (float)r[1] + b * (float)g[1];
    o0.z = a * (float)r[2] + b * (float)g[2];
    o0.w = a * (float)r[3] + b * (float)g[3];
    o1.x = a * (float)r[4] + b * (float)g[4];
    o1.y = a * (float)r[5] + b * (float)g[5];
    o1.z = a * (float)r[6] + b * (float)g[6];
    o1.w = a * (float)r[7] + b * (float)g[7];
    float4* o = (float4*)(out + (size_t)i * ND + t * 8);
    o[0] = o0;
    o[1] = o1;
    if (t < NCLS) {
      const int yi = y[i], yb = y[bi];
      const float v = a * (t == yi ? 1.0f : 0.0f) + b * (t == yb ? 1.0f : 0.0f);
      out[(size_t)NB * ND + (size_t)i * NCLS + t] = v;
    }
  }
}

// ------------------------------------------------------------------ launch --
extern "C" void kernel_launch(void* const* d_in, const int* in_sizes, int n_in,
                              void* d_out, int out_size, void* d_ws,
                              size_t ws_size, hipStream_t stream) {
  const float* x = (const float*)d_in[0];
  const int* y = (const int*)d_in[1];
  const float* alpha = (const float*)d_in[2];
  const int* beta = (const int*)d_in[3];
  const float* c = (const float*)d_in[4];
  const int* fs = (const int*)d_in[5];
  float* out = (float*)d_out;
  char* ws = (char*)d_ws;

  // workspace layout (bytes)
  unsigned char* XN8  = (unsigned char*)(ws + 0);         // 4096*2048 = 8 MiB
  unsigned char* XBT8 = (unsigned char*)(ws + 8388608);   // 2048*4096 = 8 MiB
  unsigned char* P8   = (unsigned char*)(ws + 16777216);  // 4096*4096 = 16 MiB
  bf16* R   = (bf16*)(ws + 33554432);                     // 4096*2048*2 = 16 MiB
  float* LR = (float*)(ws + 50331648);                    // 4096*4
  float* CT = (float*)(ws + 50331648 + 16384);            // 4096*4
  int* PERM = (int*)(ws + 50331648 + 32768);              // 4096*4
  int* MINFO = (int*)(ws + 50331648 + 49152);             // 3*4

  perm_kernel<<<1, 1024, 0, stream>>>(y, fs, c, PERM, MINFO, LR, CT);
  prep_kernel<<<NB + 2048, 256, 0, stream>>>(x, XN8, XBT8, PERM, MINFO);
  gemm_sim_kernel<<<640, 256, 0, stream>>>(XN8, P8, LR, PERM, MINFO);
  gemm_recon_kernel<<<512, 256, 0, stream>>>(P8, XBT8, x, LR, CT, MINFO, R);
  mix_kernel<<<NB / 2, 256, 0, stream>>>(R, alpha, beta, y, out);
}

// Round 13
// 170.301 us; speedup vs baseline: 1.2539x; 1.2539x over previous
//
#include <hip/hip_runtime.h>
#include <cstdint>
#include <cstddef>

typedef __bf16 bf16;
typedef __bf16 bf16x8 __attribute__((ext_vector_type(8)));
typedef float floatx4 __attribute__((ext_vector_type(4)));
typedef int intx8 __attribute__((ext_vector_type(8)));

#define NB 4096   // batch
#define ND 2048   // feature dim
#define NCLS 64   // classes
#define TS 80     // sim epilogue LDS row stride (bytes), 16B-aligned
#define OS 72     // recon epilogue LDS row stride (bf16 elems, 144 B)
#define SIMGRID 1280  // sim tile blocks in the merged sim+transpose kernel

// ---------------------------------------------------------------- staging ---
__device__ __forceinline__ void stage16(const void* g, void* l) {
  // async global -> LDS, 16B per lane, LDS dest = wave-uniform base + lane*16
  __builtin_amdgcn_global_load_lds(
      (__attribute__((address_space(1))) unsigned int*)g,
      (__attribute__((address_space(3))) unsigned int*)l, 16, 0, 0);
}

// fp8 e4m3 (OCP) converts, RNE via V_CVT_PK_FP8_F32
__device__ __forceinline__ unsigned char fp8x1(float f) {
  return (unsigned char)(__builtin_amdgcn_cvt_pk_fp8_f32(f, f, 0, false) & 0xFF);
}
__device__ __forceinline__ int fp8x4(float f0, float f1, float f2, float f3) {
  int d = __builtin_amdgcn_cvt_pk_fp8_f32(f0, f1, 0, false);
  return __builtin_amdgcn_cvt_pk_fp8_f32(f2, f3, d, true);
}

// ------------------------------------------------------------- GEMM core ----
// C[128][64] = A[128][K] * B[64][K]^T, fp8, fp32 accum, mfma_scale 16x16x128
// (scales=1.0 -> 127). VERIFIED R6/R10 core (169.55 us total): row-major
// 128-B LDS rows with chunk XOR-swizzle, contiguous global_load_lds staging
// for BOTH operands, double-buffered, ONE __syncthreads per K-step. All
// structural variants measured worse: reg-staged B (R7 spill), counted vmcnt
// (R8 race / R9 over-pinned), triple-buffer depth-2 (R11 null), direct-global
// A (R12 latency-serial). 48 KB LDS -> 3 blocks/CU.
// Wave w owns rows w*32..w*32+31 (M_rep 2) x all 64 cols (N_rep 4).
__device__ __forceinline__ void gemm_core64(
    const unsigned char* __restrict__ Abase, const int aoff[4],
    const unsigned char* __restrict__ Bbase, const int boff[2], int nk,
    unsigned char* __restrict__ As0, unsigned char* __restrict__ Bs0,
    unsigned char* __restrict__ As1, unsigned char* __restrict__ Bs1,
    floatx4 acc[2][4], int w, int lane) {
  const int lm = lane & 15, quad = lane >> 4;
  auto STAGE = [&](int k0, unsigned char* As, unsigned char* Bs) {
#pragma unroll
    for (int q = 0; q < 4; ++q)
      stage16(Abase + (size_t)(aoff[q] + k0), As + w * 4096 + q * 1024);
#pragma unroll
    for (int q = 0; q < 2; ++q)
      stage16(Bbase + (size_t)(boff[q] + k0), Bs + w * 2048 + q * 1024);
  };
  STAGE(0, As0, Bs0);
  for (int k = 0; k < nk; ++k) {
    __syncthreads();  // drains vmcnt(0): buf[k&1] staged; prior reads done
    if (k + 1 < nk)
      STAGE((k + 1) << 7, (k & 1) ? As0 : As1, (k & 1) ? Bs0 : Bs1);
    const unsigned char* Ac = (k & 1) ? As1 : As0;
    const unsigned char* Bc = (k & 1) ? Bs1 : Bs0;

    intx8 af[2], bf[4];
#pragma unroll
    for (int i = 0; i < 2; ++i) {
      const int row = w * 32 + i * 16 + lm;
      const int c0 = (quad * 2) ^ (row & 7);
      const int4 lo = *(const int4*)(Ac + row * 128 + c0 * 16);
      const int4 hi = *(const int4*)(Ac + row * 128 + (c0 ^ 1) * 16);
      af[i][0] = lo.x; af[i][1] = lo.y; af[i][2] = lo.z; af[i][3] = lo.w;
      af[i][4] = hi.x; af[i][5] = hi.y; af[i][6] = hi.z; af[i][7] = hi.w;
    }
#pragma unroll
    for (int i = 0; i < 4; ++i) {
      const int row = i * 16 + lm;
      const int c0 = (quad * 2) ^ (row & 7);
      const int4 lo = *(const int4*)(Bc + row * 128 + c0 * 16);
      const int4 hi = *(const int4*)(Bc + row * 128 + (c0 ^ 1) * 16);
      bf[i][0] = lo.x; bf[i][1] = lo.y; bf[i][2] = lo.z; bf[i][3] = lo.w;
      bf[i][4] = hi.x; bf[i][5] = hi.y; bf[i][6] = hi.z; bf[i][7] = hi.w;
    }
#pragma unroll
    for (int mi = 0; mi < 2; ++mi)
#pragma unroll
      for (int ni = 0; ni < 4; ++ni)
        acc[mi][ni] = __builtin_amdgcn_mfma_scale_f32_16x16x128_f8f6f4(
            af[mi], bf[ni], acc[mi][ni], 0, 0, 0, 127, 0, 127);
  }
}

// ---------------------------------------------------------------- kernels ---

// K1: block 0 = compaction (perm = sorted unmasked indices, 256-thread scan,
// 16 elems/thread); blocks 1..NB = LayerNorm rows (independent of perm).
// perm's serial ~2us hides under the 4096 LN blocks; one launch saved.
__global__ __launch_bounds__(256) void prep1_kernel(
    const float* __restrict__ x, const int* __restrict__ y,
    const int* __restrict__ fs, const float* __restrict__ c,
    unsigned char* __restrict__ XN8, int* __restrict__ perm,
    int* __restrict__ minfo, float* __restrict__ lrow,
    float* __restrict__ contrib) {
  const int t = threadIdx.x;
  __shared__ float red[2][4];
  __shared__ int wsum[4];
  __shared__ int Msh;

  if (blockIdx.x == 0) {
    // ---------------- compaction branch (16 elems per thread)
    const int base = t * 16;
    unsigned fl = 0;
    int cnt = 0;
#pragma unroll
    for (int j = 0; j < 16; ++j) {
      const int yi = y[base + j];
      const unsigned u = (fs[yi] == 0) ? 1u : 0u;
      fl |= u << j;
      cnt += (int)u;
      contrib[base + j] = c[yi];
      lrow[base + j] = 0.0f;
    }
    const int lane = t & 63, w = t >> 6;
    int inc = cnt;  // inclusive wave scan
#pragma unroll
    for (int o = 1; o < 64; o <<= 1) {
      int v = __shfl_up(inc, o);
      if (lane >= o) inc += v;
    }
    if (lane == 63) wsum[w] = inc;
    __syncthreads();
    int wbase = 0;
    for (int i = 0; i < w; ++i) wbase += wsum[i];
    int pos = wbase + inc - cnt;  // exclusive prefix
#pragma unroll
    for (int j = 0; j < 16; ++j)
      if ((fl >> j) & 1u) perm[pos++] = base + j;
    if (t == 255) Msh = wbase + inc;
    __syncthreads();
    const int M = Msh;
    const int Mp = (M + 127) & ~127;
    if (t < Mp - M) perm[M + t] = 0;  // pad: valid row 0 (exp forced 0 later)
    if (t == 0) {
      minfo[0] = M;
      minfo[1] = Mp;
      minfo[2] = Mp >> 7;
    }
    return;
  }

  // ---------------- LayerNorm branch: x row -> XN8 = fp8(x_norm*32)
  const int row = blockIdx.x - 1;
  const float4* xr = (const float4*)(x + (size_t)row * ND);
  float4 v0 = xr[t], v1 = xr[t + 256];
  float s = v0.x + v0.y + v0.z + v0.w + v1.x + v1.y + v1.z + v1.w;
  float q = v0.x * v0.x + v0.y * v0.y + v0.z * v0.z + v0.w * v0.w +
            v1.x * v1.x + v1.y * v1.y + v1.z * v1.z + v1.w * v1.w;
#pragma unroll
  for (int o = 32; o > 0; o >>= 1) {
    s += __shfl_down(s, o);
    q += __shfl_down(q, o);
  }
  const int w = t >> 6;
  if ((t & 63) == 0) { red[0][w] = s; red[1][w] = q; }
  __syncthreads();
  s = red[0][0] + red[0][1] + red[0][2] + red[0][3];
  q = red[1][0] + red[1][1] + red[1][2] + red[1][3];
  const float mu = s * (1.0f / ND);
  const float var = q * (1.0f / ND) - mu * mu;
  const float sc =
      rsqrtf(var + 1e-5f) * 0.02209708691207961f * 32.0f;  // /sqrt(2048)*32

  int* orow = (int*)(XN8 + (size_t)row * ND);
  orow[t] = fp8x4((v0.x - mu) * sc, (v0.y - mu) * sc, (v0.z - mu) * sc,
                  (v0.w - mu) * sc);
  orow[256 + t] = fp8x4((v1.x - mu) * sc, (v1.y - mu) * sc, (v1.z - mu) * sc,
                        (v1.w - mu) * sc);
}

// K2: blocks 0..SIMGRID-1 = GEMM1 (rectangular, column-compacted, 128x64
// tiles): tile (bi,bjc) computes sim[m0..][perm[n0..n0+64]]; B rows gathered
// through perm at stage time; e = exp(acc/1024), diag+pad -> 0; write P8
// tile fp8; accumulate row sums. XCD-grouped: XCD x owns bi {4x..4x+3}
// (A panels L2-resident), bi fastest -> each gathered-B tile reused x4.
// Blocks >= SIMGRID = x transpose (gathered rows x[perm[..]] -> XBT8c fp8):
// dispatched AFTER the sim blocks, they fill idle CU slots in sim's
// partially-filled second round (1216 active sim blocks on 768 slots).
__global__ __launch_bounds__(256, 3) void gemm_sim_kernel(
    const unsigned char* __restrict__ XN8, const float* __restrict__ x,
    unsigned char* __restrict__ P8, unsigned char* __restrict__ XBT8,
    float* __restrict__ lrow, const int* __restrict__ perm,
    const int* __restrict__ minfo) {
  __shared__ unsigned char smem[49152];
  const int Mp = minfo[1];
  const int t = threadIdx.x;

  if (blockIdx.x >= SIMGRID) {
    // ---------------- transpose branch: gathered x rows -> XBT8c (ND x NB)
    const int b2 = blockIdx.x - SIMGRID;
    const int rb = b2 & 63;  // compacted batch tile (0..63)
    const int cb = b2 >> 6;  // feature tile (0..31)
    if (rb * 64 >= Mp) return;  // beyond Mp: nothing to build
    float(*tile)[65] = (float(*)[65])smem;  // 64*65*4 = 16.6 KB <= 48 KB
    const int tx = t & 63, ty = t >> 6;
#pragma unroll
    for (int rr = ty; rr < 64; rr += 4)
      tile[rr][tx] = x[(size_t)perm[rb * 64 + rr] * ND + cb * 64 + tx];
    __syncthreads();
    const int ro = t >> 2;  // out row within feature tile
    const int co = t & 3;   // 16-byte chunk within batch tile
    int4 v;
    {
      const int j = co * 16;
      v.x = fp8x4(tile[j + 0][ro], tile[j + 1][ro], tile[j + 2][ro], tile[j + 3][ro]);
      v.y = fp8x4(tile[j + 4][ro], tile[j + 5][ro], tile[j + 6][ro], tile[j + 7][ro]);
      v.z = fp8x4(tile[j + 8][ro], tile[j + 9][ro], tile[j + 10][ro], tile[j + 11][ro]);
      v.w = fp8x4(tile[j + 12][ro], tile[j + 13][ro], tile[j + 14][ro], tile[j + 15][ro]);
    }
    *(int4*)(XBT8 + (size_t)(cb * 64 + ro) * NB + rb * 64 + co * 16) = v;
    return;
  }

  // ---------------- sim tile branch
  unsigned char* As0 = smem;
  unsigned char* As1 = smem + 16384;
  unsigned char* Bs0 = smem + 32768;
  unsigned char* Bs1 = smem + 40960;

  const int id = blockIdx.x;
  const int xcd = id & 7;       // round-robin dispatch -> XCD
  const int s = id >> 3;        // 0..159 within XCD
  const int bi = xcd * 4 + (s & 3);
  const int bjc = s >> 2;       // 0..39 (64-col tiles); inactive exit
  const int n0 = bjc * 64;
  if (n0 >= Mp) return;
  const int M = minfo[0];
  const int m0 = bi * 128;

  const int w = t >> 6, lane = t & 63;
  const int lm = lane & 15, quad = lane >> 4;

  int aoff[4], boff[2];
#pragma unroll
  for (int q = 0; q < 4; ++q) {
    const int slot = w * 256 + q * 64 + lane;
    const int row = slot >> 3;
    const int cc = (slot & 7) ^ (row & 7);
    aoff[q] = (m0 + row) * ND + cc * 16;
  }
#pragma unroll
  for (int q = 0; q < 2; ++q) {
    const int slot = w * 128 + q * 64 + lane;
    const int row = slot >> 3;
    const int cc = (slot & 7) ^ (row & 7);
    boff[q] = perm[n0 + row] * ND + cc * 16;  // gathered B rows
  }

  floatx4 acc[2][4];
#pragma unroll
  for (int i = 0; i < 2; ++i)
#pragma unroll
    for (int j = 0; j < 4; ++j) acc[i][j] = 0.0f;

  gemm_core64(XN8, aoff, XN8, boff, ND >> 7, As0, Bs0, As1, Bs1, acc, w, lane);

  int pcol[4], valid[4];
#pragma unroll
  for (int ni = 0; ni < 4; ++ni) {
    const int gc = n0 + ni * 16 + lm;
    valid[ni] = (gc < M) ? 1 : 0;
    pcol[ni] = perm[gc];  // original batch index of this compacted column
  }

  float rs[2][4];
#pragma unroll
  for (int mi = 0; mi < 2; ++mi)
#pragma unroll
    for (int r = 0; r < 4; ++r) rs[mi][r] = 0.0f;

#pragma unroll
  for (int ni = 0; ni < 4; ++ni) {
#pragma unroll
    for (int mi = 0; mi < 2; ++mi) {
#pragma unroll
      for (int r = 0; r < 4; ++r) {
        const int grow = m0 + w * 32 + mi * 16 + quad * 4 + r;
        const float e = (valid[ni] && grow != pcol[ni])
                            ? __expf(acc[mi][ni][r] * 0.0009765625f)
                            : 0.0f;  // diag / pad column -> exact 0
        acc[mi][ni][r] = e;
        rs[mi][r] += e;
      }
    }
  }
#pragma unroll
  for (int mi = 0; mi < 2; ++mi)
#pragma unroll
    for (int r = 0; r < 4; ++r) {
      float vsum = rs[mi][r];
      vsum += __shfl_xor(vsum, 1);
      vsum += __shfl_xor(vsum, 2);
      vsum += __shfl_xor(vsum, 4);
      vsum += __shfl_xor(vsum, 8);
      if (lm == 0)
        atomicAdd(&lrow[m0 + w * 32 + mi * 16 + quad * 4 + r], vsum);
    }

  // ---- P tile -> LDS (byte scatter) -> coalesced b128 store at (bi, bjc)
  __syncthreads();  // K-loop's last reads done in all waves; LDS reusable
#pragma unroll
  for (int ni = 0; ni < 4; ++ni) {
    const int col = ni * 16 + lm;
#pragma unroll
    for (int mi = 0; mi < 2; ++mi)
#pragma unroll
      for (int r = 0; r < 4; ++r) {
        const int row = w * 32 + mi * 16 + quad * 4 + r;
        smem[row * TS + col] = fp8x1(acc[mi][ni][r]);
      }
  }
  __syncthreads();
#pragma unroll
  for (int it = 0; it < 2; ++it) {
    const int row = it * 64 + (t >> 2), ch = t & 3;
    int4 v = *(const int4*)(smem + row * TS + ch * 16);
    *(int4*)(P8 + (size_t)(m0 + row) * NB + n0 + ch * 16) = v;
  }
}

// GEMM2 (128x64 tiles): R(bf16) = (P8[:,:Mp] @ XBT8c[:,:Mp]^T)/l * contrib
// + x*(1-contrib). K compacted to Mp. XCD-grouped by P8 ROW panels (by):
// XCD x owns by {4x..4x+3} -> its A (P8) working set is L2-resident;
// by fastest so the 4 by-tiles share each XBT B-tile from L2.
__global__ __launch_bounds__(256, 3) void gemm_recon_kernel(
    const unsigned char* __restrict__ P8, const unsigned char* __restrict__ XBT8,
    const float* __restrict__ x, const float* __restrict__ lrow,
    const float* __restrict__ contrib, const int* __restrict__ minfo,
    bf16* __restrict__ R) {
  __shared__ unsigned char smem[49152];
  unsigned char* As0 = smem;
  unsigned char* As1 = smem + 16384;
  unsigned char* Bs0 = smem + 32768;
  unsigned char* Bs1 = smem + 40960;

  const int id = blockIdx.x;
  const int xcd = id & 7;
  const int s = id >> 3;          // 0..127
  const int by = xcd * 4 + (s & 3);
  const int bx = s >> 2;          // 0..31
  const int m0 = by * 128, n0 = bx * 64;

  const int t = threadIdx.x, w = t >> 6, lane = t & 63;
  const int lm = lane & 15, quad = lane >> 4;

  int aoff[4], boff[2];
#pragma unroll
  for (int q = 0; q < 4; ++q) {
    const int slot = w * 256 + q * 64 + lane;
    const int row = slot >> 3;
    const int cc = (slot & 7) ^ (row & 7);
    aoff[q] = (m0 + row) * NB + cc * 16;
  }
#pragma unroll
  for (int q = 0; q < 2; ++q) {
    const int slot = w * 128 + q * 64 + lane;
    const int row = slot >> 3;
    const int cc = (slot & 7) ^ (row & 7);
    boff[q] = (n0 + row) * NB + cc * 16;
  }

  floatx4 acc[2][4];
#pragma unroll
  for (int i = 0; i < 2; ++i)
#pragma unroll
    for (int j = 0; j < 4; ++j) acc[i][j] = 0.0f;

  gemm_core64(P8, aoff, XBT8, boff, minfo[2], As0, Bs0, As1, Bs1, acc, w,
              lane);

  __syncthreads();  // waves done with K-loop buffers; reuse smem
  bf16* osm = (bf16*)smem;
#pragma unroll
  for (int mi = 0; mi < 2; ++mi) {
#pragma unroll
    for (int r = 0; r < 4; ++r) {
      const int lrow_i = w * 32 + mi * 16 + quad * 4 + r;
      const int grow = m0 + lrow_i;
      const float inv = 1.0f / lrow[grow];
      const float ci = contrib[grow];
#pragma unroll
      for (int ni = 0; ni < 4; ++ni) {
        const int lcol = ni * 16 + lm;
        const float rec = acc[mi][ni][r] * inv;
        const float xv = x[(size_t)grow * ND + n0 + lcol];
        osm[lrow_i * OS + lcol] = (bf16)(rec * ci + xv * (1.0f - ci));
      }
    }
  }
  __syncthreads();
#pragma unroll
  for (int it = 0; it < 4; ++it) {
    const int row = it * 32 + (t >> 3), ch = t & 7;
    int4 v = *(const int4*)(osm + row * OS + ch * 8);
    *(int4*)(R + (size_t)(m0 + row) * ND + n0 + ch * 8) = v;
  }
}

// Mix: x_mix = a*R[i] + (1-a)*R[beta[i]] (R in bf16); y_mix from one-hots.
// 2 rows per block (grid NB/2) to cut launch/scheduling overhead.
__global__ __launch_bounds__(256) void mix_kernel(
    const bf16* __restrict__ R, const float* __restrict__ alpha,
    const int* __restrict__ beta_idx, const int* __restrict__ y,
    float* __restrict__ out) {
  const int t = threadIdx.x;
#pragma unroll
  for (int rr = 0; rr < 2; ++rr) {
    const int i = blockIdx.x * 2 + rr;
    const float a = alpha[i];
    const int bi = beta_idx[i];
    const bf16x8* Ri = (const bf16x8*)(R + (size_t)i * ND);
    const bf16x8* Rb = (const bf16x8*)(R + (size_t)bi * ND);
    const float b = 1.0f - a;
    bf16x8 r = Ri[t], g = Rb[t];
    float4 o0, o1;
    o0.x = a * (float)r[0] + b * (float)g[0];
    o0.y = a * (float)r[1] + b * (float)g[1];
    o0.z = a * (float)r[2] + b * (float)g[2];
    o0.w = a * (float)r[3] + b * (float)g[3];
    o1.x = a * (float)r[4] + b * (float)g[4];
    o1.y = a * (float)r[5] + b * (float)g[5];
    o1.z = a * (float)r[6] + b * (float)g[6];
    o1.w = a * (float)r[7] + b * (float)g[7];
    float4* o = (float4*)(out + (size_t)i * ND + t * 8);
    o[0] = o0;
    o[1] = o1;
    if (t < NCLS) {
      const int yi = y[i], yb = y[bi];
      const float v = a * (t == yi ? 1.0f : 0.0f) + b * (t == yb ? 1.0f : 0.0f);
      out[(size_t)NB * ND + (size_t)i * NCLS + t] = v;
    }
  }
}

// ------------------------------------------------------------------ launch --
extern "C" void kernel_launch(void* const* d_in, const int* in_sizes, int n_in,
                              void* d_out, int out_size, void* d_ws,
                              size_t ws_size, hipStream_t stream) {
  const float* x = (const float*)d_in[0];
  const int* y = (const int*)d_in[1];
  const float* alpha = (const float*)d_in[2];
  const int* beta = (const int*)d_in[3];
  const float* c = (const float*)d_in[4];
  const int* fs = (const int*)d_in[5];
  float* out = (float*)d_out;
  char* ws = (char*)d_ws;

  // workspace layout (bytes)
  unsigned char* XN8  = (unsigned char*)(ws + 0);         // 4096*2048 = 8 MiB
  unsigned char* XBT8 = (unsigned char*)(ws + 8388608);   // 2048*4096 = 8 MiB
  unsigned char* P8   = (unsigned char*)(ws + 16777216);  // 4096*4096 = 16 MiB
  bf16* R   = (bf16*)(ws + 33554432);                     // 4096*2048*2 = 16 MiB
  float* LR = (float*)(ws + 50331648);                    // 4096*4
  float* CT = (float*)(ws + 50331648 + 16384);            // 4096*4
  int* PERM = (int*)(ws + 50331648 + 32768);              // 4096*4
  int* MINFO = (int*)(ws + 50331648 + 49152);             // 3*4

  prep1_kernel<<<NB + 1, 256, 0, stream>>>(x, y, fs, c, XN8, PERM, MINFO, LR,
                                           CT);
  gemm_sim_kernel<<<SIMGRID + 2048, 256, 0, stream>>>(XN8, x, P8, XBT8, LR,
                                                      PERM, MINFO);
  gemm_recon_kernel<<<1024, 256, 0, stream>>>(P8, XBT8, x, LR, CT, MINFO, R);
  mix_kernel<<<NB / 2, 256, 0, stream>>>(R, alpha, beta, y, out);
}

// Round 14
// 167.696 us; speedup vs baseline: 1.2734x; 1.0155x over previous
//
#include <hip/hip_runtime.h>
#include <cstdint>
#include <cstddef>

typedef __bf16 bf16;
typedef __bf16 bf16x8 __attribute__((ext_vector_type(8)));
typedef float floatx4 __attribute__((ext_vector_type(4)));
typedef int intx8 __attribute__((ext_vector_type(8)));

#define NB 4096   // batch
#define ND 2048   // feature dim
#define NCLS 64   // classes
#define TS 80     // sim epilogue LDS row stride (bytes), 16B-aligned
#define OS 72     // recon epilogue LDS row stride (bf16 elems, 144 B)

// ---------------------------------------------------------------- staging ---
__device__ __forceinline__ void stage16(const void* g, void* l) {
  // async global -> LDS, 16B per lane, LDS dest = wave-uniform base + lane*16
  __builtin_amdgcn_global_load_lds(
      (__attribute__((address_space(1))) unsigned int*)g,
      (__attribute__((address_space(3))) unsigned int*)l, 16, 0, 0);
}

// fp8 e4m3 (OCP) converts, RNE via V_CVT_PK_FP8_F32
__device__ __forceinline__ unsigned char fp8x1(float f) {
  return (unsigned char)(__builtin_amdgcn_cvt_pk_fp8_f32(f, f, 0, false) & 0xFF);
}
__device__ __forceinline__ int fp8x4(float f0, float f1, float f2, float f3) {
  int d = __builtin_amdgcn_cvt_pk_fp8_f32(f0, f1, 0, false);
  return __builtin_amdgcn_cvt_pk_fp8_f32(f2, f3, d, true);
}

// ------------------------------------------------------------- GEMM core ----
// C[128][64] = A[128][K] * B[64][K]^T, fp8, fp32 accum, mfma_scale 16x16x128
// (scales=1.0 -> 127). VERIFIED R6/R10 core (169.55 us total): row-major
// 128-B LDS rows with chunk XOR-swizzle, contiguous global_load_lds staging
// for BOTH operands, double-buffered, ONE __syncthreads per K-step. All
// structural variants measured worse or neutral: reg-staged B (R7 spill),
// counted vmcnt (R8 race / R9 over-pinned), triple-buffer depth-2 (R11
// null), direct-global A (R12 latency-serial), kernel fusion (R13 neutral).
// 48 KB LDS -> 3 blocks/CU. Staging runs at ~46 B/cy/CU (~80% of the L2
// ceiling) — the binding resource of this structure class.
// Wave w owns rows w*32..w*32+31 (M_rep 2) x all 64 cols (N_rep 4).
__device__ __forceinline__ void gemm_core64(
    const unsigned char* __restrict__ Abase, const int aoff[4],
    const unsigned char* __restrict__ Bbase, const int boff[2], int nk,
    unsigned char* __restrict__ As0, unsigned char* __restrict__ Bs0,
    unsigned char* __restrict__ As1, unsigned char* __restrict__ Bs1,
    floatx4 acc[2][4], int w, int lane) {
  const int lm = lane & 15, quad = lane >> 4;
  auto STAGE = [&](int k0, unsigned char* As, unsigned char* Bs) {
#pragma unroll
    for (int q = 0; q < 4; ++q)
      stage16(Abase + (size_t)(aoff[q] + k0), As + w * 4096 + q * 1024);
#pragma unroll
    for (int q = 0; q < 2; ++q)
      stage16(Bbase + (size_t)(boff[q] + k0), Bs + w * 2048 + q * 1024);
  };
  STAGE(0, As0, Bs0);
  for (int k = 0; k < nk; ++k) {
    __syncthreads();  // drains vmcnt(0): buf[k&1] staged; prior reads done
    if (k + 1 < nk)
      STAGE((k + 1) << 7, (k & 1) ? As0 : As1, (k & 1) ? Bs0 : Bs1);
    const unsigned char* Ac = (k & 1) ? As1 : As0;
    const unsigned char* Bc = (k & 1) ? Bs1 : Bs0;

    intx8 af[2], bf[4];
#pragma unroll
    for (int i = 0; i < 2; ++i) {
      const int row = w * 32 + i * 16 + lm;
      const int c0 = (quad * 2) ^ (row & 7);
      const int4 lo = *(const int4*)(Ac + row * 128 + c0 * 16);
      const int4 hi = *(const int4*)(Ac + row * 128 + (c0 ^ 1) * 16);
      af[i][0] = lo.x; af[i][1] = lo.y; af[i][2] = lo.z; af[i][3] = lo.w;
      af[i][4] = hi.x; af[i][5] = hi.y; af[i][6] = hi.z; af[i][7] = hi.w;
    }
#pragma unroll
    for (int i = 0; i < 4; ++i) {
      const int row = i * 16 + lm;
      const int c0 = (quad * 2) ^ (row & 7);
      const int4 lo = *(const int4*)(Bc + row * 128 + c0 * 16);
      const int4 hi = *(const int4*)(Bc + row * 128 + (c0 ^ 1) * 16);
      bf[i][0] = lo.x; bf[i][1] = lo.y; bf[i][2] = lo.z; bf[i][3] = lo.w;
      bf[i][4] = hi.x; bf[i][5] = hi.y; bf[i][6] = hi.z; bf[i][7] = hi.w;
    }
#pragma unroll
    for (int mi = 0; mi < 2; ++mi)
#pragma unroll
      for (int ni = 0; ni < 4; ++ni)
        acc[mi][ni] = __builtin_amdgcn_mfma_scale_f32_16x16x128_f8f6f4(
            af[mi], bf[ni], acc[mi][ni], 0, 0, 0, 127, 0, 127);
  }
}

// ---------------------------------------------------------------- kernels ---

// Compaction: perm = sorted indices i with fs[y[i]]==0 (the only columns that
// survive the softmax mask). minfo = {M, Mp(=ceil128), Mp/128}. Pad perm with
// 0 (valid row) so padded staging never fabricates fp8 NaNs. Also init lrow,
// contrib here (single tiny block, runs before everything else).
__global__ __launch_bounds__(1024) void perm_kernel(
    const int* __restrict__ y, const int* __restrict__ fs,
    const float* __restrict__ c, int* __restrict__ perm,
    int* __restrict__ minfo, float* __restrict__ lrow,
    float* __restrict__ contrib) {
  const int t = threadIdx.x;
  const int base = t * 4;
  int fl[4];
  int cnt = 0;
#pragma unroll
  for (int j = 0; j < 4; ++j) {
    const int yi = y[base + j];
    fl[j] = (fs[yi] == 0) ? 1 : 0;
    cnt += fl[j];
    contrib[base + j] = c[yi];
    lrow[base + j] = 0.0f;
  }
  // inclusive scan of cnt across the block (wave scan + inter-wave sum)
  const int lane = t & 63, w = t >> 6;
  int inc = cnt;
#pragma unroll
  for (int o = 1; o < 64; o <<= 1) {
    int v = __shfl_up(inc, o);
    if (lane >= o) inc += v;
  }
  __shared__ int wsum[16];
  __shared__ int Msh;
  if (lane == 63) wsum[w] = inc;
  __syncthreads();
  int wbase = 0;
  for (int i = 0; i < w; ++i) wbase += wsum[i];
  int pos = wbase + inc - cnt;  // exclusive prefix
#pragma unroll
  for (int j = 0; j < 4; ++j)
    if (fl[j]) perm[pos++] = base + j;
  if (t == 1023) Msh = wbase + inc;
  __syncthreads();
  const int M = Msh;
  const int Mp = (M + 127) & ~127;
  if (t < Mp - M) perm[M + t] = 0;
  if (t == 0) {
    minfo[0] = M;
    minfo[1] = Mp;
    minfo[2] = Mp >> 7;
  }
}

// Fused prep: blocks 0..NB-1 do LayerNorm (x -> XN8 = fp8(x_norm*32));
// blocks NB.. transpose GATHERED rows x[perm[..]] -> XBT8c (fp8, columns
// already compacted; row stride stays NB).
__global__ __launch_bounds__(256) void prep_kernel(
    const float* __restrict__ x, unsigned char* __restrict__ XN8,
    unsigned char* __restrict__ XBT8, const int* __restrict__ perm,
    const int* __restrict__ minfo) {
  __shared__ float tile[64][65];
  const int t = threadIdx.x;

  if (blockIdx.x < NB) {
    // ---------------- LayerNorm branch
    const int row = blockIdx.x;
    const float4* xr = (const float4*)(x + (size_t)row * ND);
    float4 v0 = xr[t], v1 = xr[t + 256];
    float s = v0.x + v0.y + v0.z + v0.w + v1.x + v1.y + v1.z + v1.w;
    float q = v0.x * v0.x + v0.y * v0.y + v0.z * v0.z + v0.w * v0.w +
              v1.x * v1.x + v1.y * v1.y + v1.z * v1.z + v1.w * v1.w;
#pragma unroll
    for (int o = 32; o > 0; o >>= 1) {
      s += __shfl_down(s, o);
      q += __shfl_down(q, o);
    }
    const int w = t >> 6;
    if ((t & 63) == 0) { tile[0][w] = s; tile[1][w] = q; }
    __syncthreads();
    s = tile[0][0] + tile[0][1] + tile[0][2] + tile[0][3];
    q = tile[1][0] + tile[1][1] + tile[1][2] + tile[1][3];
    const float mu = s * (1.0f / ND);
    const float var = q * (1.0f / ND) - mu * mu;
    const float sc =
        rsqrtf(var + 1e-5f) * 0.02209708691207961f * 32.0f;  // /sqrt(2048)*32

    int* orow = (int*)(XN8 + (size_t)row * ND);
    orow[t] = fp8x4((v0.x - mu) * sc, (v0.y - mu) * sc, (v0.z - mu) * sc,
                    (v0.w - mu) * sc);
    orow[256 + t] = fp8x4((v1.x - mu) * sc, (v1.y - mu) * sc, (v1.z - mu) * sc,
                          (v1.w - mu) * sc);
  } else {
    // ---------------- transpose branch: gathered x rows -> XBT8c (ND x NB)
    const int b2 = blockIdx.x - NB;
    const int rb = b2 & 63;  // compacted batch tile (0..63)
    const int cb = b2 >> 6;  // feature tile (0..31)
    if (rb * 64 >= minfo[1]) return;  // beyond Mp: nothing to build
    const int tx = t & 63, ty = t >> 6;
#pragma unroll
    for (int rr = ty; rr < 64; rr += 4)
      tile[rr][tx] = x[(size_t)perm[rb * 64 + rr] * ND + cb * 64 + tx];
    __syncthreads();
    const int ro = t >> 2;  // out row within feature tile
    const int co = t & 3;   // 16-byte chunk within batch tile
    int4 v;
    {
      const int j = co * 16;
      v.x = fp8x4(tile[j + 0][ro], tile[j + 1][ro], tile[j + 2][ro], tile[j + 3][ro]);
      v.y = fp8x4(tile[j + 4][ro], tile[j + 5][ro], tile[j + 6][ro], tile[j + 7][ro]);
      v.z = fp8x4(tile[j + 8][ro], tile[j + 9][ro], tile[j + 10][ro], tile[j + 11][ro]);
      v.w = fp8x4(tile[j + 12][ro], tile[j + 13][ro], tile[j + 14][ro], tile[j + 15][ro]);
    }
    *(int4*)(XBT8 + (size_t)(cb * 64 + ro) * NB + rb * 64 + co * 16) = v;
  }
}

// GEMM1 (rectangular, column-compacted, 128x64 tiles): tile (bi, bjc)
// computes sim[m0..][perm[n0..n0+64]]; B rows gathered through perm at stage
// time. e = exp(acc/1024), diag + pad -> 0; write P8 tile fp8; accumulate
// row sums. XCD-grouped: XCD x owns bi {4x..4x+3} (A panels 1 MiB L2-
// resident), bi fastest so each gathered-B tile is reused x4 from L2.
// 48 KB LDS + (256,3) -> 3 blocks/CU.
__global__ __launch_bounds__(256, 3) void gemm_sim_kernel(
    const unsigned char* __restrict__ XN8, unsigned char* __restrict__ P8,
    float* __restrict__ lrow, const int* __restrict__ perm,
    const int* __restrict__ minfo) {
  __shared__ unsigned char smem[49152];
  unsigned char* As0 = smem;
  unsigned char* As1 = smem + 16384;
  unsigned char* Bs0 = smem + 32768;
  unsigned char* Bs1 = smem + 40960;

  const int Mp = minfo[1];
  const int id = blockIdx.x;
  const int xcd = id & 7;       // round-robin dispatch -> XCD
  const int s = id >> 3;        // 0..159 within XCD
  const int bi = xcd * 4 + (s & 3);
  const int bjc = s >> 2;       // 0..39 (64-col tiles); inactive exit
  const int n0 = bjc * 64;
  if (n0 >= Mp) return;
  const int M = minfo[0];
  const int m0 = bi * 128;

  const int t = threadIdx.x, w = t >> 6, lane = t & 63;
  const int lm = lane & 15, quad = lane >> 4;

  int aoff[4], boff[2];
#pragma unroll
  for (int q = 0; q < 4; ++q) {
    const int slot = w * 256 + q * 64 + lane;
    const int row = slot >> 3;
    const int cc = (slot & 7) ^ (row & 7);
    aoff[q] = (m0 + row) * ND + cc * 16;
  }
#pragma unroll
  for (int q = 0; q < 2; ++q) {
    const int slot = w * 128 + q * 64 + lane;
    const int row = slot >> 3;
    const int cc = (slot & 7) ^ (row & 7);
    boff[q] = perm[n0 + row] * ND + cc * 16;  // gathered B rows
  }

  floatx4 acc[2][4];
#pragma unroll
  for (int i = 0; i < 2; ++i)
#pragma unroll
    for (int j = 0; j < 4; ++j) acc[i][j] = 0.0f;

  gemm_core64(XN8, aoff, XN8, boff, ND >> 7, As0, Bs0, As1, Bs1, acc, w, lane);

  int pcol[4], valid[4];
#pragma unroll
  for (int ni = 0; ni < 4; ++ni) {
    const int gc = n0 + ni * 16 + lm;
    valid[ni] = (gc < M) ? 1 : 0;
    pcol[ni] = perm[gc];  // original batch index of this compacted column
  }

  float rs[2][4];
#pragma unroll
  for (int mi = 0; mi < 2; ++mi)
#pragma unroll
    for (int r = 0; r < 4; ++r) rs[mi][r] = 0.0f;

#pragma unroll
  for (int ni = 0; ni < 4; ++ni) {
#pragma unroll
    for (int mi = 0; mi < 2; ++mi) {
#pragma unroll
      for (int r = 0; r < 4; ++r) {
        const int grow = m0 + w * 32 + mi * 16 + quad * 4 + r;
        const float e = (valid[ni] && grow != pcol[ni])
                            ? __expf(acc[mi][ni][r] * 0.0009765625f)
                            : 0.0f;  // diag / pad column -> exact 0
        acc[mi][ni][r] = e;
        rs[mi][r] += e;
      }
    }
  }
#pragma unroll
  for (int mi = 0; mi < 2; ++mi)
#pragma unroll
    for (int r = 0; r < 4; ++r) {
      float vsum = rs[mi][r];
      vsum += __shfl_xor(vsum, 1);
      vsum += __shfl_xor(vsum, 2);
      vsum += __shfl_xor(vsum, 4);
      vsum += __shfl_xor(vsum, 8);
      if (lm == 0)
        atomicAdd(&lrow[m0 + w * 32 + mi * 16 + quad * 4 + r], vsum);
    }

  // ---- P tile -> LDS (byte scatter) -> coalesced b128 store at (bi, bjc)
  __syncthreads();  // K-loop's last reads done in all waves; LDS reusable
#pragma unroll
  for (int ni = 0; ni < 4; ++ni) {
    const int col = ni * 16 + lm;
#pragma unroll
    for (int mi = 0; mi < 2; ++mi)
#pragma unroll
      for (int r = 0; r < 4; ++r) {
        const int row = w * 32 + mi * 16 + quad * 4 + r;
        smem[row * TS + col] = fp8x1(acc[mi][ni][r]);
      }
  }
  __syncthreads();
#pragma unroll
  for (int it = 0; it < 2; ++it) {
    const int row = it * 64 + (t >> 2), ch = t & 3;
    int4 v = *(const int4*)(smem + row * TS + ch * 16);
    *(int4*)(P8 + (size_t)(m0 + row) * NB + n0 + ch * 16) = v;
  }
}

// GEMM2 (128x64 tiles): R(bf16) = (P8[:,:Mp] @ XBT8c[:,:Mp]^T)/l * contrib
// + x*(1-contrib). K compacted to Mp. XCD-grouped by P8 ROW panels (by):
// XCD x owns by {4x..4x+3} -> its A (P8) working set is L2-resident;
// by fastest so the 4 by-tiles share each XBT B-tile from L2.
__global__ __launch_bounds__(256, 3) void gemm_recon_kernel(
    const unsigned char* __restrict__ P8, const unsigned char* __restrict__ XBT8,
    const float* __restrict__ x, const float* __restrict__ lrow,
    const float* __restrict__ contrib, const int* __restrict__ minfo,
    bf16* __restrict__ R) {
  __shared__ unsigned char smem[49152];
  unsigned char* As0 = smem;
  unsigned char* As1 = smem + 16384;
  unsigned char* Bs0 = smem + 32768;
  unsigned char* Bs1 = smem + 40960;

  const int id = blockIdx.x;
  const int xcd = id & 7;
  const int s = id >> 3;          // 0..127
  const int by = xcd * 4 + (s & 3);
  const int bx = s >> 2;          // 0..31
  const int m0 = by * 128, n0 = bx * 64;

  const int t = threadIdx.x, w = t >> 6, lane = t & 63;
  const int lm = lane & 15, quad = lane >> 4;

  int aoff[4], boff[2];
#pragma unroll
  for (int q = 0; q < 4; ++q) {
    const int slot = w * 256 + q * 64 + lane;
    const int row = slot >> 3;
    const int cc = (slot & 7) ^ (row & 7);
    aoff[q] = (m0 + row) * NB + cc * 16;
  }
#pragma unroll
  for (int q = 0; q < 2; ++q) {
    const int slot = w * 128 + q * 64 + lane;
    const int row = slot >> 3;
    const int cc = (slot & 7) ^ (row & 7);
    boff[q] = (n0 + row) * NB + cc * 16;
  }

  floatx4 acc[2][4];
#pragma unroll
  for (int i = 0; i < 2; ++i)
#pragma unroll
    for (int j = 0; j < 4; ++j) acc[i][j] = 0.0f;

  gemm_core64(P8, aoff, XBT8, boff, minfo[2], As0, Bs0, As1, Bs1, acc, w,
              lane);

  __syncthreads();  // waves done with K-loop buffers; reuse smem
  bf16* osm = (bf16*)smem;
#pragma unroll
  for (int mi = 0; mi < 2; ++mi) {
#pragma unroll
    for (int r = 0; r < 4; ++r) {
      const int lrow_i = w * 32 + mi * 16 + quad * 4 + r;
      const int grow = m0 + lrow_i;
      const float inv = 1.0f / lrow[grow];
      const float ci = contrib[grow];
#pragma unroll
      for (int ni = 0; ni < 4; ++ni) {
        const int lcol = ni * 16 + lm;
        const float rec = acc[mi][ni][r] * inv;
        const float xv = x[(size_t)grow * ND + n0 + lcol];
        osm[lrow_i * OS + lcol] = (bf16)(rec * ci + xv * (1.0f - ci));
      }
    }
  }
  __syncthreads();
#pragma unroll
  for (int it = 0; it < 4; ++it) {
    const int row = it * 32 + (t >> 3), ch = t & 7;
    int4 v = *(const int4*)(osm + row * OS + ch * 8);
    *(int4*)(R + (size_t)(m0 + row) * ND + n0 + ch * 8) = v;
  }
}

// Mix: x_mix = a*R[i] + (1-a)*R[beta[i]] (R in bf16); y_mix from one-hots.
// 4 rows per block (grid NB/4) to cut launch/scheduling overhead.
__global__ __launch_bounds__(256) void mix_kernel(
    const bf16* __restrict__ R, const float* __restrict__ alpha,
    const int* __restrict__ beta_idx, const int* __restrict__ y,
    float* __restrict__ out) {
  const int t = threadIdx.x;
#pragma unroll
  for (int rr = 0; rr < 4; ++rr) {
    const int i = blockIdx.x * 4 + rr;
    const float a = alpha[i];
    const int bi = beta_idx[i];
    const bf16x8* Ri = (const bf16x8*)(R + (size_t)i * ND);
    const bf16x8* Rb = (const bf16x8*)(R + (size_t)bi * ND);
    const float b = 1.0f - a;
    bf16x8 r = Ri[t], g = Rb[t];
    float4 o0, o1;
    o0.x = a * (float)r[0] + b * (float)g[0];
    o0.y = a * (float)r[1] + b * (float)g[1];
    o0.z = a * (float)r[2] + b * (float)g[2];
    o0.w = a * (float)r[3] + b * (float)g[3];
    o1.x = a * (float)r[4] + b * (float)g[4];
    o1.y = a * (float)r[5] + b * (float)g[5];
    o1.z = a * (float)r[6] + b * (float)g[6];
    o1.w = a * (float)r[7] + b * (float)g[7];
    float4* o = (float4*)(out + (size_t)i * ND + t * 8);
    o[0] = o0;
    o[1] = o1;
    if (t < NCLS) {
      const int yi = y[i], yb = y[bi];
      const float v = a * (t == yi ? 1.0f : 0.0f) + b * (t == yb ? 1.0f : 0.0f);
      out[(size_t)NB * ND + (size_t)i * NCLS + t] = v;
    }
  }
}

// ------------------------------------------------------------------ launch --
extern "C" void kernel_launch(void* const* d_in, const int* in_sizes, int n_in,
                              void* d_out, int out_size, void* d_ws,
                              size_t ws_size, hipStream_t stream) {
  const float* x = (const float*)d_in[0];
  const int* y = (const int*)d_in[1];
  const float* alpha = (const float*)d_in[2];
  const int* beta = (const int*)d_in[3];
  const float* c = (const float*)d_in[4];
  const int* fs = (const int*)d_in[5];
  float* out = (float*)d_out;
  char* ws = (char*)d_ws;

  // workspace layout (bytes)
  unsigned char* XN8  = (unsigned char*)(ws + 0);         // 4096*2048 = 8 MiB
  unsigned char* XBT8 = (unsigned char*)(ws + 8388608);   // 2048*4096 = 8 MiB
  unsigned char* P8   = (unsigned char*)(ws + 16777216);  // 4096*4096 = 16 MiB
  bf16* R   = (bf16*)(ws + 33554432);                     // 4096*2048*2 = 16 MiB
  float* LR = (float*)(ws + 50331648);                    // 4096*4
  float* CT = (float*)(ws + 50331648 + 16384);            // 4096*4
  int* PERM = (int*)(ws + 50331648 + 32768);              // 4096*4
  int* MINFO = (int*)(ws + 50331648 + 49152);             // 3*4

  perm_kernel<<<1, 1024, 0, stream>>>(y, fs, c, PERM, MINFO, LR, CT);
  prep_kernel<<<NB + 2048, 256, 0, stream>>>(x, XN8, XBT8, PERM, MINFO);
  gemm_sim_kernel<<<1280, 256, 0, stream>>>(XN8, P8, LR, PERM, MINFO);
  gemm_recon_kernel<<<1024, 256, 0, stream>>>(P8, XBT8, x, LR, CT, MINFO, R);
  mix_kernel<<<NB / 4, 256, 0, stream>>>(R, alpha, beta, y, out);
}